// Round 1
// 247.705 us; speedup vs baseline: 1.0314x; 1.0314x over previous
//
#include <hip/hip_runtime.h>
#include <math.h>

// ---- static config (mirrors reference) ----
constexpr int BB  = 32;     // batch
constexpr int MM  = 20;     // max gt per image
constexpr int NCC = 80;     // classes
constexpr int RM  = 16;     // reg_max
constexpr int NOC = 144;    // channels per head
constexpr int AT  = 8400;   // anchors
constexpr int TK  = 10;     // topk
constexpr int BA  = BB * AT;  // 268800
constexpr int BM  = BB * MM;  // 640
constexpr int MAXPOS = BM * TK; // 6400 topk entries
constexpr int NSLOT = 1024;     // max candidates per gt
constexpr float EPS_A = 1e-9f;
constexpr float VCOEF = 0.40528473456935108577551785283891f; // 4/pi^2

// feature-pass grid layout
constexpr int NBOX0 = BB * 6400 / 256;   // 800 decode blocks, level 0
constexpr int NBOX1 = BB * 1600 / 256;   // 200 decode blocks, level 1
constexpr int NBOX2 = BB * 400 / 256;    //  50 decode blocks, level 2
constexpr int NBOX  = NBOX0 + NBOX1 + NBOX2;  // 1050
constexpr int NBCE  = 2048;              // BCE streaming blocks
// class-channel float4 chunks per image: 80*HW/4 per level
constexpr unsigned C0F4 = 80 * 6400 / 4; // 128000
constexpr unsigned C1F4 = 80 * 1600 / 4; // 32000
constexpr unsigned C2F4 = 80 * 400 / 4;  // 8000
constexpr unsigned CBF4 = C0F4 + C1F4 + C2F4;  // 168000
constexpr unsigned NF4  = (unsigned)BB * CBF4; // 5376000

struct Lvl { const float* f; int o, w, hw; float s; };

__device__ inline Lvl level_of(int a, const float* f0, const float* f1, const float* f2){
  Lvl L;
  if (a < 6400)      { L.f = f0; L.o = a;        L.w = 80; L.hw = 6400; L.s = 8.f;  }
  else if (a < 8000) { L.f = f1; L.o = a - 6400; L.w = 40; L.hw = 1600; L.s = 16.f; }
  else               { L.f = f2; L.o = a - 8000; L.w = 20; L.hw = 400;  L.s = 32.f; }
  return L;
}

__device__ inline float frcp(float x){ return __builtin_amdgcn_rcpf(x); }

// fast atan, |err| < ~2e-6
__device__ inline float fast_atan(float x){
  float ax = fabsf(x);
  bool big = ax > 1.f;
  float z = big ? frcp(ax) : ax;
  float z2 = z * z;
  float p = fmaf(z2, -0.0117212f, 0.0526533f);
  p = fmaf(z2, p, -0.1164329f);
  p = fmaf(z2, p, 0.1935435f);
  p = fmaf(z2, p, -0.3326235f);
  p = fmaf(z2, p, 0.9999773f);
  float r = z * p;
  r = big ? 1.57079632679f - r : r;
  return copysignf(r, x);
}

__device__ inline float ciou_f(float b1x1,float b1y1,float b1x2,float b1y2,
                               float b2x1,float b2y1,float b2x2,float b2y2){
  const float eps = 1e-7f;
  float w1 = b1x2 - b1x1, h1 = b1y2 - b1y1 + eps;
  float w2 = b2x2 - b2x1, h2 = b2y2 - b2y1 + eps;
  float iw = fmaxf(fminf(b1x2, b2x2) - fmaxf(b1x1, b2x1), 0.f);
  float ih = fmaxf(fminf(b1y2, b2y2) - fmaxf(b1y1, b2y1), 0.f);
  float inter = iw * ih;
  float uni = w1 * h1 + w2 * h2 - inter + eps;
  float iou = inter * frcp(uni);
  float cw = fmaxf(b1x2, b2x2) - fminf(b1x1, b2x1);
  float ch = fmaxf(b1y2, b2y2) - fminf(b1y1, b2y1);
  float c2 = cw * cw + ch * ch + eps;
  float dx = b2x1 + b2x2 - b1x1 - b1x2;
  float dy = b2y1 + b2y2 - b1y1 - b1y2;
  float rho2 = (dx * dx + dy * dy) * 0.25f;
  float r1 = w1 * frcp(h1), r2 = w2 * frcp(h2);
  float dat = fast_atan((r2 - r1) * frcp(fmaf(r1, r2, 1.f)));
  float v = VCOEF * dat * dat;
  float alpha = v * frcp(v - iou + (1.0f + eps));
  return iou - (rho2 * frcp(c2) + v * alpha);
}

__device__ inline unsigned long long shfl_xor_u64(unsigned long long v, int mask){
  int lo = __shfl_xor((int)(unsigned)(v & 0xFFFFFFFFull), mask);
  int hi = __shfl_xor((int)(unsigned)(v >> 32), mask);
  return ((unsigned long long)(unsigned)hi << 32) | (unsigned)lo;
}

__device__ inline float softplus4(float4 v){
  float s = fmaxf(v.x, 0.f) + __logf(1.f + __expf(-fabsf(v.x)));
  s += fmaxf(v.y, 0.f) + __logf(1.f + __expf(-fabsf(v.y)));
  s += fmaxf(v.z, 0.f) + __logf(1.f + __expf(-fabsf(v.z)));
  s += fmaxf(v.w, 0.f) + __logf(1.f + __expf(-fabsf(v.w)));
  return s;
}

// ---------------- fused feature pass ----------------
// decode: one thread per anchor, no LDS, no barriers, in-register softmax.
// Loads are wave-coalesced: lane i reads channel j at base+i, 256B/transaction.
template<int HW, int W, int AOFF>
__device__ inline void decode_anchor(const float* __restrict__ f, int u,
                                     float4* __restrict__ pbox,
                                     float4* __restrict__ lseg,
                                     unsigned* __restrict__ mpos){
  int b = u / HW, o = u - b * HW;
  const float* base = f + (size_t)b * NOC * HW + o;
  float d[4], ls[4];
#pragma unroll
  for (int side = 0; side < 4; side++){
    float x[16];
#pragma unroll
    for (int j = 0; j < 16; j++)
      x[j] = base[(size_t)((side * 16 + j) * HW)];
    float mx = x[0];
#pragma unroll
    for (int j = 1; j < 16; j++) mx = fmaxf(mx, x[j]);
    float sm = 0.f, dt = 0.f;
#pragma unroll
    for (int j = 0; j < 16; j++){
      float e = __expf(x[j] - mx);
      sm += e; dt = fmaf(e, (float)j, dt);
    }
    d[side]  = dt * frcp(sm);
    ls[side] = mx + __logf(sm);
  }
  int iy = o / W;
  float ax = (float)(o - iy * W) + 0.5f;
  float ay = (float)iy + 0.5f;
  int gi = b * AT + AOFF + o;
  pbox[gi] = make_float4(ax - d[0], ay - d[1], ax + d[2], ay + d[3]);
  lseg[gi] = make_float4(ls[0], ls[1], ls[2], ls[3]);
  mpos[gi] = 0u;
}

__global__ __launch_bounds__(256) void k_feat2(
    const float* __restrict__ f0, const float* __restrict__ f1,
    const float* __restrict__ f2, const float* __restrict__ tgt,
    float4* __restrict__ pbox, float4* __restrict__ lse,
    unsigned* __restrict__ mpos, double* __restrict__ bce_part,
    float* __restrict__ out5, float* __restrict__ gtbox,
    int* __restrict__ gtlab, float* __restrict__ gtmask,
    int* __restrict__ pa_i, int* __restrict__ po_i,
    int* __restrict__ topk_arr, double* __restrict__ acc){
  __shared__ float red[4];
  int blk = blockIdx.x;
  int tid = threadIdx.x;
  if (blk < NBOX){
    // ---- DFL bbox decode, one thread per anchor ----
    if (blk < NBOX0){
      decode_anchor<6400, 80, 0>(f0, blk * 256 + tid, pbox, lse, mpos);
    } else if (blk < NBOX0 + NBOX1){
      decode_anchor<1600, 40, 6400>(f1, (blk - NBOX0) * 256 + tid, pbox, lse, mpos);
    } else {
      decode_anchor<400, 20, 8000>(f2, (blk - NBOX0 - NBOX1) * 256 + tid, pbox, lse, mpos);
    }
  } else if (blk < NBOX + NBCE){
    // ---- BCE softplus sum: pure float4 stream over class channels ----
    int bi = blk - NBOX;
    float sp = 0.f;
    for (unsigned i = (unsigned)bi * 256u + (unsigned)tid; i < NF4;
         i += (unsigned)NBCE * 256u){
      unsigned b = i / CBF4;
      unsigned r = i - b * CBF4;
      const float4* p;
      if (r < C0F4)
        p = (const float4*)(f0) + (size_t)b * (NOC * 6400 / 4) + (64 * 6400 / 4) + r;
      else if (r < C0F4 + C1F4)
        p = (const float4*)(f1) + (size_t)b * (NOC * 1600 / 4) + (64 * 1600 / 4) + (r - C0F4);
      else
        p = (const float4*)(f2) + (size_t)b * (NOC * 400 / 4) + (64 * 400 / 4) + (r - C0F4 - C1F4);
      sp += softplus4(*p);
    }
    for (int off = 32; off; off >>= 1) sp += __shfl_down(sp, off);
    int wid = tid >> 6, lid = tid & 63;
    if (lid == 0) red[wid] = sp;
    __syncthreads();
    if (tid == 0) bce_part[bi] = (double)(red[0] + red[1] + red[2] + red[3]);
  } else {
    // ---- prep block (former k_prep), 256 threads ----
    for (int i = tid; i < BM * 5; i += 256) out5[i] = 0.f;
    for (int i = tid; i < MAXPOS; i += 256) topk_arr[i] = -1;
    for (int i = tid; i < BM; i += 256){ pa_i[i] = 0; po_i[i] = 0; }
    if (tid < 8) acc[tid] = 0.0;
    __syncthreads();
    for (int t = tid; t < BM; t += 256){
      int img = (int)tgt[t * 6 + 0];
      int j = t;
      while (j > 0 && (int)tgt[(j - 1) * 6 + 0] == img) j--;
      int pos = t - j;
      if (img >= 0 && img < BB && pos < MM){
        for (int k = 0; k < 5; k++)
          out5[(img * MM + pos) * 5 + k] = tgt[t * 6 + 1 + k];
      }
    }
    __syncthreads();
    for (int t = tid; t < BM; t += 256){
      float lab = out5[t * 5 + 0];
      float cx = out5[t * 5 + 1] * 640.f;
      float cy = out5[t * 5 + 2] * 640.f;
      float w  = out5[t * 5 + 3] * 640.f;
      float h  = out5[t * 5 + 4] * 640.f;
      float x1 = cx - w * 0.5f, y1 = cy - h * 0.5f;
      float x2 = cx + w * 0.5f, y2 = cy + h * 0.5f;
      gtbox[t * 4 + 0] = x1; gtbox[t * 4 + 1] = y1;
      gtbox[t * 4 + 2] = x2; gtbox[t * 4 + 3] = y2;
      gtlab[t] = (int)lab;
      gtmask[t] = ((x1 + y1 + x2 + y2) > 0.f) ? 1.f : 0.f;
    }
  }
}

// ---------------- kernel 3: candidate LDS table + 10x block argmax ----------------
__global__ __launch_bounds__(256) void k_align(
    const float* __restrict__ f0, const float* __restrict__ f1,
    const float* __restrict__ f2, const float4* __restrict__ pbox,
    const float* __restrict__ gtbox, const int* __restrict__ gtlab,
    const float* __restrict__ gtmask,
    unsigned* __restrict__ mpos, int* __restrict__ topk_arr){
  int pair = blockIdx.x;
  int b = pair / MM, m = pair % MM;
  if (gtmask[pair] <= 0.f) return;  // topk_arr pre-inited to -1
  int tid = threadIdx.x;
  float gx1 = gtbox[pair * 4 + 0], gy1 = gtbox[pair * 4 + 1];
  float gx2 = gtbox[pair * 4 + 2], gy2 = gtbox[pair * 4 + 3];
  int lab = gtlab[pair];
  __shared__ float s_val[NSLOT];
  __shared__ int   s_anc[NSLOT];
  __shared__ unsigned long long s_red[4];
  __shared__ int   s_win[TK];
  int base = 0;

#define PROC_LEVEL(FPTR, W, HW, AOFF, S)                                      \
  {                                                                           \
    const float s_ = (S); const float inv_ = 1.f / (S);                       \
    int x0 = max(0, (int)floorf(gx1 * inv_ - 0.5f));                          \
    int x1 = min((W) - 1, (int)ceilf(gx2 * inv_ - 0.5f));                     \
    int y0 = max(0, (int)floorf(gy1 * inv_ - 0.5f));                          \
    int y1 = min((W) - 1, (int)ceilf(gy2 * inv_ - 0.5f));                     \
    int nxx = x1 - x0 + 1, nyy = y1 - y0 + 1;                                 \
    if (nxx > 0 && nyy > 0){                                                  \
      int ntot = nxx * nyy;                                                   \
      unsigned magic = 0xFFFFFFFFu / (unsigned)nxx + 1u;                      \
      const float* clsrow = (FPTR) + (size_t)b * NOC * (HW)                   \
                            + (size_t)(4 * RM + lab) * (HW);                  \
      for (int t = tid; t < ntot; t += 256){                                  \
        int slot = base + t;                                                  \
        if (slot >= NSLOT) break;                                             \
        int iy = (int)(((unsigned long long)(unsigned)t * magic) >> 32);      \
        int ix = t - iy * nxx + x0;                                           \
        iy += y0;                                                             \
        float ax = ((float)ix + 0.5f) * s_;                                   \
        float ay = ((float)iy + 0.5f) * s_;                                   \
        float mn = fminf(fminf(ax - gx1, ay - gy1),                           \
                         fminf(gx2 - ax, gy2 - ay));                          \
        int o = iy * (W) + ix;                                                \
        int a = (AOFF) + o;                                                   \
        float aln = -1.f;                                                     \
        if (mn > EPS_A){                                                      \
          float4 pb = pbox[b * AT + a];                                       \
          float c = ciou_f(gx1, gy1, gx2, gy2,                                \
                           pb.x * s_, pb.y * s_, pb.z * s_, pb.w * s_);       \
          float ovl = fmaxf(c, 0.f);                                          \
          if (ovl > 0.f){                                                     \
            float xv = clsrow[o];                                             \
            float sc = frcp(1.f + __expf(-xv));                               \
            float o2 = ovl * ovl;                                             \
            aln = sqrtf(sc) * (o2 * o2 * o2);                                 \
          }                                                                   \
        }                                                                     \
        s_val[slot] = aln;                                                    \
        s_anc[slot] = a;                                                      \
      }                                                                       \
      base += ntot;                                                           \
    }                                                                         \
  }

  PROC_LEVEL(f0, 80, 6400, 0, 8.f)
  PROC_LEVEL(f1, 40, 1600, 6400, 16.f)
  PROC_LEVEL(f2, 20, 400, 8000, 32.f)
#undef PROC_LEVEL

  __syncthreads();
  int total = min(base, NSLOT);
  int wid = tid >> 6, lid = tid & 63;
  for (int r = 0; r < TK; r++){
    unsigned long long key = 0ULL;
    for (int i = tid; i < total; i += 256){
      float v = s_val[i];
      if (v > 0.f){
        unsigned long long k2 =
            ((unsigned long long)__float_as_uint(v) << 32) |
            (unsigned long long)(0xFFFFFFFFu - (unsigned)i);
        key = key > k2 ? key : k2;
      }
    }
    for (int xm = 1; xm < 64; xm <<= 1){
      unsigned long long o = shfl_xor_u64(key, xm);
      key = key > o ? key : o;
    }
    if (lid == 0) s_red[wid] = key;
    __syncthreads();
    if (tid == 0){
      unsigned long long k = s_red[0];
      k = k > s_red[1] ? k : s_red[1];
      k = k > s_red[2] ? k : s_red[2];
      k = k > s_red[3] ? k : s_red[3];
      if (k){
        int slot = (int)(0xFFFFFFFFu - (unsigned)(k & 0xFFFFFFFFull));
        s_win[r] = s_anc[slot];
        s_val[slot] = -1.f;
      } else s_win[r] = -1;
    }
    __syncthreads();
  }
  if (tid < TK){
    int a = s_win[tid];
    topk_arr[pair * TK + tid] = a;
    if (a >= 0) atomicOr(&mpos[(size_t)b * AT + a], 1u << m);
  }
}

// ---------------- kernel 4: resolve multi-claims, pos maxima ----------------
__global__ __launch_bounds__(256) void k_resolve(
    const float* __restrict__ f0, const float* __restrict__ f1,
    const float* __restrict__ f2, const float4* __restrict__ pbox,
    const float* __restrict__ gtbox, const int* __restrict__ gtlab,
    const float* __restrict__ gtmask, const unsigned* __restrict__ mpos,
    const int* __restrict__ topk_arr,
    unsigned char* __restrict__ resm, float* __restrict__ resaln,
    int* __restrict__ pa_i, int* __restrict__ po_i){
  int i = blockIdx.x * 256 + threadIdx.x;  // 0..MAXPOS-1
  int a = topk_arr[i];
  if (a < 0) return;
  int pair = i / TK;
  int b = pair / MM, m = pair % MM;
  unsigned bits = mpos[(size_t)b * AT + a];
  if (m != __ffs(bits) - 1) return;        // one thread per positive anchor
  Lvl L = level_of(a, f0, f1, f2);
  float ax = ((float)(L.o % L.w) + 0.5f) * L.s;
  float ay = ((float)(L.o / L.w) + 0.5f) * L.s;
  float4 pb = pbox[b * AT + a];
  float px1 = pb.x * L.s, py1 = pb.y * L.s, px2 = pb.z * L.s, py2 = pb.w * L.s;
  int mr; float ovl;
  if (__popc(bits) > 1){
    float best = -1.f; int bm = 0;
    for (int mm = 0; mm < MM; mm++){
      float v = 0.f;
      if (gtmask[b * MM + mm] > 0.f){
        float x1 = gtbox[(b * MM + mm) * 4 + 0], y1 = gtbox[(b * MM + mm) * 4 + 1];
        float x2 = gtbox[(b * MM + mm) * 4 + 2], y2 = gtbox[(b * MM + mm) * 4 + 3];
        float mn = fminf(fminf(ax - x1, ay - y1), fminf(x2 - ax, y2 - ay));
        if (mn > EPS_A)
          v = fmaxf(ciou_f(x1, y1, x2, y2, px1, py1, px2, py2), 0.f);
      }
      if (v > best){ best = v; bm = mm; }
    }
    mr = bm; ovl = fmaxf(best, 0.f);
  } else {
    mr = m;
    float x1 = gtbox[(b * MM + mr) * 4 + 0], y1 = gtbox[(b * MM + mr) * 4 + 1];
    float x2 = gtbox[(b * MM + mr) * 4 + 2], y2 = gtbox[(b * MM + mr) * 4 + 3];
    ovl = fmaxf(ciou_f(x1, y1, x2, y2, px1, py1, px2, py2), 0.f);
  }
  int lab = gtlab[b * MM + mr];
  float xv = L.f[(size_t)b * NOC * L.hw + (size_t)(4 * RM + lab) * L.hw + L.o];
  float sc = frcp(1.f + __expf(-xv));
  float o2 = ovl * ovl;
  float aln = sqrtf(sc) * (o2 * o2 * o2);
  size_t gi = (size_t)b * AT + a;
  resm[gi] = (unsigned char)mr;
  resaln[gi] = aln;
  atomicMax(&pa_i[b * MM + mr], __float_as_int(aln));
  atomicMax(&po_i[b * MM + mr], __float_as_int(ovl));
}

// ---------------- kernel 5: per-positive losses ----------------
__global__ __launch_bounds__(256) void k_final(
    const float* __restrict__ f0, const float* __restrict__ f1,
    const float* __restrict__ f2,
    const float4* __restrict__ pbox, const float4* __restrict__ lse,
    const float* __restrict__ gtbox, const int* __restrict__ gtlab,
    const int* __restrict__ pa_i, const int* __restrict__ po_i,
    const unsigned* __restrict__ mpos, const int* __restrict__ topk_arr,
    const unsigned char* __restrict__ resm, const float* __restrict__ resaln,
    double* __restrict__ acc){
  int i = blockIdx.x * 256 + threadIdx.x;
  float w_ = 0.f, clsp = 0.f, boxp = 0.f, dflp = 0.f;
  int a = topk_arr[i];
  if (a >= 0){
    int pair = i / TK;
    int b = pair / MM, m = pair % MM;
    unsigned bits = mpos[(size_t)b * AT + a];
    if (m == __ffs(bits) - 1){
      size_t gi = (size_t)b * AT + a;
      int mr = (int)resm[gi];
      float aln = resaln[gi];
      float pa = __int_as_float(pa_i[b * MM + mr]);
      float po = __int_as_float(po_i[b * MM + mr]);
      w_ = aln * po * frcp(pa + EPS_A);
      Lvl L = level_of(a, f0, f1, f2);
      const float* base = L.f + (size_t)b * NOC * L.hw + L.o;
      float ax = (float)(L.o % L.w) + 0.5f;
      float ay = (float)(L.o / L.w) + 0.5f;
      float inv_s = frcp(L.s);
      float tx1 = gtbox[(b * MM + mr) * 4 + 0] * inv_s, ty1 = gtbox[(b * MM + mr) * 4 + 1] * inv_s;
      float tx2 = gtbox[(b * MM + mr) * 4 + 2] * inv_s, ty2 = gtbox[(b * MM + mr) * 4 + 3] * inv_s;
      float4 pb = pbox[b * AT + a];
      float iou = ciou_f(pb.x, pb.y, pb.z, pb.w, tx1, ty1, tx2, ty2);
      boxp = (1.f - iou) * w_;
      float4 L4 = lse[b * AT + a];
      float lsv[4] = { L4.x, L4.y, L4.z, L4.w };
      float tv[4] = { ax - tx1, ay - ty1, tx2 - ax, ty2 - ay };
      float dfl = 0.f;
#pragma unroll
      for (int s4 = 0; s4 < 4; s4++){
        float t = fminf(fmaxf(tv[s4], 0.f), (float)(RM - 1) - 0.01f);
        int tl = (int)t;
        float wl = (float)(tl + 1) - t;
        float xl = base[(size_t)(s4 * RM + tl) * L.hw];
        float xr = base[(size_t)(s4 * RM + tl + 1) * L.hw];
        dfl += (lsv[s4] - xl) * wl + (lsv[s4] - xr) * (1.f - wl);
      }
      dflp = dfl * 0.25f * w_;
      int lab = gtlab[b * MM + mr];
      clsp = base[(size_t)(4 * RM + lab) * L.hw] * w_;
    }
  }
  __shared__ float red[4][4];
  float vals[4] = { w_, clsp, boxp, dflp };
  int wid = threadIdx.x >> 6, lid = threadIdx.x & 63;
#pragma unroll
  for (int j = 0; j < 4; j++){
    float v = vals[j];
    for (int off = 32; off; off >>= 1) v += __shfl_down(v, off);
    if (lid == 0) red[wid][j] = v;
  }
  __syncthreads();
  if (threadIdx.x == 0){
    float t0 = 0.f, t1 = 0.f, t2 = 0.f, t3 = 0.f;
    for (int w2 = 0; w2 < 4; w2++){
      t0 += red[w2][0]; t1 += red[w2][1]; t2 += red[w2][2]; t3 += red[w2][3];
    }
    atomicAdd(&acc[0], (double)t0);
    atomicAdd(&acc[1], (double)t1);
    atomicAdd(&acc[2], (double)t2);
    atomicAdd(&acc[3], (double)t3);
  }
}

// ---------------- kernel 6: finalize (reduce BCE partials + output) ----------------
__global__ void k_out(const double* __restrict__ acc,
                      const double* __restrict__ bce_part,
                      float* __restrict__ out){
  __shared__ double sd[256];
  double s = 0.0;
  for (int i = threadIdx.x; i < NBCE; i += 256) s += bce_part[i];
  sd[threadIdx.x] = s;
  __syncthreads();
  for (int off = 128; off; off >>= 1){
    if (threadIdx.x < off) sd[threadIdx.x] += sd[threadIdx.x + off];
    __syncthreads();
  }
  if (threadIdx.x == 0){
    double bce_sum = sd[0];
    double tss = acc[0] > 1.0 ? acc[0] : 1.0;
    double loss_box = acc[2] / tss;
    double loss_cls = (bce_sum - acc[1]) / tss;
    double loss_dfl = acc[3] / tss;
    float l0 = (float)(loss_box * 7.5);
    float l1 = (float)(loss_cls * 0.5);
    float l2 = (float)(loss_dfl * 1.5);
    out[0] = (l0 + l1 + l2) * 32.f;
    out[1] = l0;
    out[2] = l1;
    out[3] = l2;
  }
}

extern "C" void kernel_launch(void* const* d_in, const int* in_sizes, int n_in,
                              void* d_out, int out_size, void* d_ws, size_t ws_size,
                              hipStream_t stream) {
  const float* f0 = (const float*)d_in[0];
  const float* f1 = (const float*)d_in[1];
  const float* f2 = (const float*)d_in[2];
  const float* tg = (const float*)d_in[3];
  float* out = (float*)d_out;

  char* w = (char*)d_ws;
  size_t off = 0;
  auto alloc = [&](size_t bytes) -> void* {
    void* p = w + off;
    off += (bytes + 255) & ~(size_t)255;
    return p;
  };
  float4*        pbox    = (float4*)       alloc((size_t)BA * 16);
  float4*        lse     = (float4*)       alloc((size_t)BA * 16);
  float*         gtbox   = (float*)        alloc((size_t)BM * 16);
  int*           gtlab   = (int*)          alloc((size_t)BM * 4);
  float*         gtmask  = (float*)        alloc((size_t)BM * 4);
  float*         out5    = (float*)        alloc((size_t)BM * 20);
  unsigned*      mpos    = (unsigned*)     alloc((size_t)BA * 4);  // zeroed by decode blocks
  int*           topk_arr= (int*)          alloc((size_t)MAXPOS * 4); // -1 by prep block
  unsigned char* resm    = (unsigned char*)alloc((size_t)BA);      // write-before-read
  float*         resaln  = (float*)        alloc((size_t)BA * 4);  // write-before-read
  int*           pa      = (int*)          alloc((size_t)BM * 4);
  int*           po      = (int*)          alloc((size_t)BM * 4);
  double*        acc     = (double*)       alloc(8 * 8);
  double*        bcep    = (double*)       alloc((size_t)NBCE * 8); // written unconditionally

  k_feat2<<<NBOX + NBCE + 1, 256, 0, stream>>>(f0, f1, f2, tg, pbox, lse, mpos, bcep,
                                               out5, gtbox, gtlab, gtmask, pa, po,
                                               topk_arr, acc);
  k_align<<<BM, 256, 0, stream>>>(f0, f1, f2, pbox, gtbox, gtlab, gtmask, mpos, topk_arr);
  k_resolve<<<MAXPOS / 256, 256, 0, stream>>>(f0, f1, f2, pbox, gtbox, gtlab, gtmask,
                                              mpos, topk_arr, resm, resaln, pa, po);
  k_final<<<MAXPOS / 256, 256, 0, stream>>>(f0, f1, f2, pbox, lse, gtbox, gtlab,
                                            pa, po, mpos, topk_arr, resm, resaln, acc);
  k_out<<<1, 256, 0, stream>>>(acc, bcep, out);
}